// Round 1
// baseline (169.604 us; speedup 1.0000x reference)
//
#include <hip/hip_runtime.h>
#include <math.h>

// Workspace layout (first 64 bytes zeroed via hipMemsetAsync):
//   ws + 0  : int   pos_count (P)
//   ws + 4  : int   neg_count
//   ws + 16 : double pos_loss
//   ws + 24 : double neg_loss

#define MAXL 1024

// Kernel 1: scan all N anchors. For positive anchors: count P, match GT label,
// compute regression target t, gather 4 reg + 2 cls values for every batch,
// accumulate positive loss.
__global__ void k_pos_scan(const float* __restrict__ anchor,
                           const float* __restrict__ label,
                           const float* __restrict__ cla,
                           const float* __restrict__ reg,
                           const int* __restrict__ dA,
                           const int* __restrict__ dF,
                           const int* __restrict__ dC,
                           int N, int L, int B,
                           int* __restrict__ cnt,
                           double* __restrict__ pos_loss) {
    const int A = *dA;
    const int F = *dF;
    const float Cf = (float)(*dC);

    __shared__ float sh_cls[MAXL];
    __shared__ int sh_occ[MAXL];
    const bool useLds = (L <= MAXL);
    if (useLds) {
        for (int j = threadIdx.x; j < L; j += blockDim.x)
            sh_cls[j] = label[(size_t)j * 5];
        __syncthreads();
        for (int j = threadIdx.x; j < L; j += blockDim.x) {
            float c = sh_cls[j];
            int o = 0;
            for (int k = 0; k < j; ++k) o += (sh_cls[k] == c) ? 1 : 0;
            sh_occ[j] = o;
        }
        __syncthreads();
    }

    int n = blockIdx.x * blockDim.x + threadIdx.x;
    if (n >= N) return;

    const float* a = anchor + (size_t)n * 7;
    float albl = a[1];
    if (albl == -1.0f || albl == Cf) return;   // not a positive anchor

    atomicAdd(cnt, 1);

    float ax = a[2], ay = a[3], aw = a[4], ah = a[5], aocc = a[6];

    // first label j with (class match && occurrence match); argmax(all-false)=0
    int gt = 0;
    for (int j = 0; j < L; ++j) {
        float cj;
        int oj;
        if (useLds) { cj = sh_cls[j]; oj = sh_occ[j]; }
        else {
            cj = label[(size_t)j * 5];
            oj = 0;
            for (int k = 0; k < j; ++k) oj += (label[(size_t)k * 5] == cj) ? 1 : 0;
        }
        if (cj == albl && (float)oj == aocc) { gt = j; break; }
    }
    const float* g = label + (size_t)gt * 5;
    float t0 = (g[1] - ax) / aw;
    float t1 = (g[2] - ay) / ah;
    float t2 = logf(g[3] / aw);
    float t3 = logf(g[4] / ah);

    int tmp = n / A;
    int ai  = n - tmp * A;
    int h   = tmp % F;
    int w   = tmp / F;
    int c4  = ai * 4;
    int c2  = ai * 2;
    size_t hw = (size_t)F * F;

    double acc = 0.0;
    for (int b = 0; b < B; ++b) {
        size_t regBase = (((size_t)b * (4 * A) + c4) * F + h) * F + w;
        float r0 = reg[regBase];
        float r1 = reg[regBase + hw];
        float r2 = reg[regBase + 2 * hw];
        float r3 = reg[regBase + 3 * hw];
        float d0 = r0 - t0, d1 = r1 - t1, d2 = r2 - t2, d3 = r3 - t3;

        float ad, sl, lr = 0.0f;
        ad = fabsf(d0); sl = (ad < 1.0f) ? 0.5f * d0 * d0 : ad - 0.5f; lr += sl;
        ad = fabsf(d1); sl = (ad < 1.0f) ? 0.5f * d1 * d1 : ad - 0.5f; lr += sl;
        ad = fabsf(d2); sl = (ad < 1.0f) ? 0.5f * d2 * d2 : ad - 0.5f; lr += sl;
        ad = fabsf(d3); sl = (ad < 1.0f) ? 0.5f * d3 * d3 : ad - 0.5f; lr += sl;
        lr *= 0.25f;

        size_t claBase = (((size_t)b * (2 * A) + c2) * F + h) * F + w;
        float x0 = cla[claBase];
        float x1 = cla[claBase + hw];
        float m = fmaxf(x0, x1);
        float lse = m + logf(expf(x0 - m) + expf(x1 - m));
        float lcp = lse - x1;  // -log_softmax[...,1]

        acc += (double)(lcp + 4.0f * lr);
    }
    atomicAdd(pos_loss, acc);
}

// Kernel 2: negatives. One wave (64 lanes) per batch row; ballot/popcount
// running prefix over S samples for the inclusive cumsum; gather cls pairs
// for included negatives.
__global__ void k_neg(const float* __restrict__ cla,
                      const float* __restrict__ anchor,
                      const int* __restrict__ neg,
                      const int* __restrict__ dA,
                      const int* __restrict__ dF,
                      const int* __restrict__ dC,
                      int S,
                      const int* __restrict__ cnt,
                      double* __restrict__ neg_loss,
                      int* __restrict__ neg_cnt) {
    const int A = *dA;
    const int F = *dF;
    const float Cf = (float)(*dC);
    const int P = *cnt;
    const int limit = 3 * P;

    int b = blockIdx.x;
    int lane = threadIdx.x;  // 0..63
    size_t hw = (size_t)F * F;

    int base = 0;         // negatives seen in previous chunks
    float lsum = 0.0f;
    int lcnt = 0;

    for (int c0 = 0; c0 < S; c0 += 64) {
        int s = c0 + lane;
        bool valid = s < S;
        int idx = valid ? neg[(size_t)b * S + s] : 0;
        float lbl = valid ? anchor[(size_t)idx * 7 + 1] : -2.0f;
        bool isneg = valid && (lbl == Cf);

        unsigned long long mask = __ballot(isneg);
        int pre = __popcll(mask & ((1ull << lane) - 1ull));
        int cum = base + pre + (isneg ? 1 : 0);  // inclusive cumsum

        if (isneg && cum <= limit) {
            int tmp = idx / A;
            int ai  = idx - tmp * A;
            int h   = tmp % F;
            int w   = tmp / F;
            int c2  = ai * 2;
            size_t claBase = (((size_t)b * (2 * A) + c2) * F + h) * F + w;
            float x0 = cla[claBase];
            float x1 = cla[claBase + hw];
            float m = fmaxf(x0, x1);
            float lse = m + logf(expf(x0 - m) + expf(x1 - m));
            lsum += (lse - x0);  // -log_softmax[...,0]
            lcnt += 1;
        }
        base += __popcll(mask);
    }

    // wave reduction
    for (int off = 32; off > 0; off >>= 1) {
        lsum += __shfl_down(lsum, off, 64);
        lcnt += __shfl_down(lcnt, off, 64);
    }
    if (lane == 0) {
        if (lsum != 0.0f) atomicAdd(neg_loss, (double)lsum);
        if (lcnt != 0) atomicAdd(neg_cnt, lcnt);
    }
}

__global__ void k_final(const int* __restrict__ cnt,
                        const int* __restrict__ neg_cnt,
                        const double* __restrict__ pos_loss,
                        const double* __restrict__ neg_loss,
                        int B,
                        float* __restrict__ out) {
    float denom = (float)(B * (*cnt) + (*neg_cnt));
    out[0] = (float)(*pos_loss + *neg_loss) / denom;
}

extern "C" void kernel_launch(void* const* d_in, const int* in_sizes, int n_in,
                              void* d_out, int out_size, void* d_ws, size_t ws_size,
                              hipStream_t stream) {
    const float* cla    = (const float*)d_in[0];
    const float* reg    = (const float*)d_in[1];
    const float* label  = (const float*)d_in[2];
    const float* anchor = (const float*)d_in[3];
    const int*   neg    = (const int*)d_in[4];
    const int*   dA     = (const int*)d_in[5];
    const int*   dF     = (const int*)d_in[6];
    const int*   dC     = (const int*)d_in[7];

    int N = in_sizes[3] / 7;           // A*F*F
    int L = in_sizes[2] / 5;           // num labels
    int B = in_sizes[0] / (2 * N);     // cla_map = B*2A*F*F = 2*B*N
    int S = in_sizes[4] / B;           // neg samples per batch

    char* ws = (char*)d_ws;
    int*    cnt      = (int*)(ws + 0);
    int*    neg_cnt  = (int*)(ws + 4);
    double* pos_loss = (double*)(ws + 16);
    double* neg_loss = (double*)(ws + 24);

    hipMemsetAsync(ws, 0, 64, stream);

    int blk = 256;
    int grid = (N + blk - 1) / blk;
    k_pos_scan<<<grid, blk, 0, stream>>>(anchor, label, cla, reg, dA, dF, dC,
                                         N, L, B, cnt, pos_loss);
    k_neg<<<B, 64, 0, stream>>>(cla, anchor, neg, dA, dF, dC, S,
                                cnt, neg_loss, neg_cnt);
    k_final<<<1, 1, 0, stream>>>(cnt, neg_cnt, pos_loss, neg_loss, B,
                                 (float*)d_out);
}

// Round 4
// 157.144 us; speedup vs baseline: 1.0793x; 1.0793x over previous
//
#include <hip/hip_runtime.h>
#include <math.h>

#define MAXL 256

// Workspace layout (first 64 bytes zeroed via hipMemsetAsync):
//   ws + 0  : int    pos_count (P)
//   ws + 4  : int    neg_count
//   ws + 16 : double pos_loss
//   ws + 24 : double neg_loss
//   ws + 64 : PosRec records (compacted positive anchors)
struct __align__(16) PosRec {
    float t0, t1, t2, t3;
    int c2, h, w, pad;
};

// ---- Kernel 1: scan anchors, compute targets, compact positives ----
__global__ void __launch_bounds__(256)
k_scan(const float* __restrict__ anchor,
       const float* __restrict__ label,
       const int* __restrict__ dA,
       const int* __restrict__ dF,
       const int* __restrict__ dC,
       int N, int L, int maxRec,
       int* __restrict__ cnt,
       PosRec* __restrict__ recs)
{
    const int A = *dA;
    const int F = *dF;
    const float Cf = (float)(*dC);

    __shared__ float sh_cls[MAXL];
    __shared__ int   sh_occ[MAXL];
    const bool useLds = (L <= MAXL);
    if (useLds) {
        for (int j = threadIdx.x; j < L; j += blockDim.x)
            sh_cls[j] = label[(size_t)j * 5];
        __syncthreads();
        for (int j = threadIdx.x; j < L; j += blockDim.x) {
            float c = sh_cls[j];
            int o = 0;
            for (int k = 0; k < j; ++k) o += (sh_cls[k] == c) ? 1 : 0;
            sh_occ[j] = o;
        }
        __syncthreads();
    }

    const int tid = blockIdx.x * blockDim.x + threadIdx.x;
    const int nth = gridDim.x * blockDim.x;

    for (int n = tid; n < N; n += nth) {
        float albl = anchor[(size_t)n * 7 + 1];
        if (albl == -1.0f || albl == Cf) continue;

        float ax   = anchor[(size_t)n * 7 + 2];
        float ay   = anchor[(size_t)n * 7 + 3];
        float aw   = anchor[(size_t)n * 7 + 4];
        float ah   = anchor[(size_t)n * 7 + 5];
        float aocc = anchor[(size_t)n * 7 + 6];

        // first j with (class match && occurrence match); argmax(all-false)=0
        int gt = 0;
        for (int j = 0; j < L; ++j) {
            float cj; int oj;
            if (useLds) { cj = sh_cls[j]; oj = sh_occ[j]; }
            else {
                cj = label[(size_t)j * 5];
                oj = 0;
                for (int k = 0; k < j; ++k) oj += (label[(size_t)k * 5] == cj) ? 1 : 0;
            }
            if (cj == albl && (float)oj == aocc) { gt = j; break; }
        }
        const float* g = label + (size_t)gt * 5;

        PosRec r;
        r.t0 = (g[1] - ax) / aw;
        r.t1 = (g[2] - ay) / ah;
        r.t2 = logf(g[3] / aw);
        r.t3 = logf(g[4] / ah);
        int tmp = n / A;
        int ai  = n - tmp * A;
        r.h = tmp % F;
        r.w = tmp / F;
        r.c2 = ai * 2;
        r.pad = 0;

        int slot = atomicAdd(cnt, 1);
        if (slot < maxRec) recs[slot] = r;
    }
}

// ---- Kernel 2: fused pos (blocks [0,16)) + neg (blocks [16,16+8)) ----
#define POS_BLOCKS 16
#define NEG_BLOCKS 8

__global__ void __launch_bounds__(256)
k_loss(const float* __restrict__ cla,
       const float* __restrict__ reg,
       const float* __restrict__ anchor,
       const int* __restrict__ neg,
       const int* __restrict__ dA,
       const int* __restrict__ dF,
       const int* __restrict__ dC,
       int B, int S,
       const int* __restrict__ cnt,
       const PosRec* __restrict__ recs,
       double* __restrict__ pos_loss,
       double* __restrict__ neg_loss,
       int* __restrict__ neg_cnt)
{
    const int A = *dA;
    const int F = *dF;
    const size_t hw = (size_t)F * F;
    const int P = *cnt;
    const int lane = threadIdx.x & 63;

    if (blockIdx.x < POS_BLOCKS) {
        // -------- positive losses: P*B independent tasks --------
        const int tid = blockIdx.x * blockDim.x + threadIdx.x;
        const int nth = POS_BLOCKS * blockDim.x;
        const int T = P * B;

        double acc = 0.0;
        for (int task = tid; task < T; task += nth) {
            int p = task / B;
            int b = task - p * B;
            PosRec r = recs[p];
            int c4 = r.c2 * 2;

            size_t regBase = (((size_t)b * (4 * A) + c4) * F + r.h) * F + r.w;
            float d0 = reg[regBase]          - r.t0;
            float d1 = reg[regBase +     hw] - r.t1;
            float d2 = reg[regBase + 2 * hw] - r.t2;
            float d3 = reg[regBase + 3 * hw] - r.t3;

            float lr = 0.0f, ad;
            ad = fabsf(d0); lr += (ad < 1.0f) ? 0.5f * d0 * d0 : ad - 0.5f;
            ad = fabsf(d1); lr += (ad < 1.0f) ? 0.5f * d1 * d1 : ad - 0.5f;
            ad = fabsf(d2); lr += (ad < 1.0f) ? 0.5f * d2 * d2 : ad - 0.5f;
            ad = fabsf(d3); lr += (ad < 1.0f) ? 0.5f * d3 * d3 : ad - 0.5f;
            lr *= 0.25f;

            size_t claBase = (((size_t)b * (2 * A) + r.c2) * F + r.h) * F + r.w;
            float x0 = cla[claBase];
            float x1 = cla[claBase + hw];
            float m  = fmaxf(x0, x1);
            float lse = m + logf(expf(x0 - m) + expf(x1 - m));

            acc += (double)((lse - x1) + 4.0f * lr);
        }
        for (int off = 32; off > 0; off >>= 1) acc += __shfl_down(acc, off, 64);
        if (lane == 0 && acc != 0.0) atomicAdd(pos_loss, acc);
    } else {
        // -------- negatives: one wave per batch row --------
        const float Cf = (float)(*dC);
        int gwave = (blockIdx.x - POS_BLOCKS) * (blockDim.x >> 6) + (threadIdx.x >> 6);
        if (gwave >= B) return;
        int b = gwave;
        const int limit = 3 * P;

        int base = 0;
        float lsum = 0.0f;
        int lcnt = 0;
        for (int c0 = 0; c0 < S; c0 += 64) {
            int s = c0 + lane;
            bool valid = (s < S);
            int idx   = valid ? neg[(size_t)b * S + s] : 0;
            float lbl = valid ? anchor[(size_t)idx * 7 + 1] : -2.0f;
            bool isneg = valid && (lbl == Cf);

            unsigned long long mask = __ballot(isneg);
            int pre = __popcll(mask & ((1ull << lane) - 1ull));
            int cum = base + pre + (isneg ? 1 : 0);   // inclusive cumsum

            if (isneg && cum <= limit) {
                int tmp = idx / A;
                int ai  = idx - tmp * A;
                int h   = tmp % F;
                int w2  = tmp / F;
                size_t claBase = (((size_t)b * (2 * A) + ai * 2) * F + h) * F + w2;
                float x0 = cla[claBase];
                float x1 = cla[claBase + hw];
                float m  = fmaxf(x0, x1);
                lsum += m + logf(expf(x0 - m) + expf(x1 - m)) - x0;
                lcnt += 1;
            }
            base += __popcll(mask);
        }
        for (int off = 32; off > 0; off >>= 1) {
            lsum += __shfl_down(lsum, off, 64);
            lcnt += __shfl_down(lcnt, off, 64);
        }
        if (lane == 0 && lcnt != 0) {
            atomicAdd(neg_loss, (double)lsum);
            atomicAdd(neg_cnt, lcnt);
        }
    }
}

// ---- Kernel 3: finalize ----
__global__ void k_final(const int* __restrict__ cnt,
                        const int* __restrict__ neg_cnt,
                        const double* __restrict__ pos_loss,
                        const double* __restrict__ neg_loss,
                        int B,
                        float* __restrict__ out)
{
    double denom = (double)(B * (*cnt) + (*neg_cnt));
    out[0] = (float)((*pos_loss + *neg_loss) / denom);
}

extern "C" void kernel_launch(void* const* d_in, const int* in_sizes, int n_in,
                              void* d_out, int out_size, void* d_ws, size_t ws_size,
                              hipStream_t stream) {
    const float* cla    = (const float*)d_in[0];
    const float* reg    = (const float*)d_in[1];
    const float* label  = (const float*)d_in[2];
    const float* anchor = (const float*)d_in[3];
    const int*   neg    = (const int*)d_in[4];
    const int*   dA     = (const int*)d_in[5];
    const int*   dF     = (const int*)d_in[6];
    const int*   dC     = (const int*)d_in[7];

    int N = in_sizes[3] / 7;           // A*F*F
    int L = in_sizes[2] / 5;           // num labels
    int B = in_sizes[0] / (2 * N);     // batch
    int S = in_sizes[4] / B;           // neg samples per batch

    char* ws = (char*)d_ws;
    int*    cnt      = (int*)(ws + 0);
    int*    neg_cnt  = (int*)(ws + 4);
    double* pos_loss = (double*)(ws + 16);
    double* neg_loss = (double*)(ws + 24);
    PosRec* recs     = (PosRec*)(ws + 64);
    int maxRec = (int)((ws_size - 64) / sizeof(PosRec));

    hipMemsetAsync(ws, 0, 64, stream);

    int scanGrid = 128;   // grid-stride over N
    k_scan<<<scanGrid, 256, 0, stream>>>(anchor, label, dA, dF, dC,
                                         N, L, maxRec, cnt, recs);

    int negBlocks = (B + 3) / 4;              // 4 waves per 256-thread block
    int lossGrid = POS_BLOCKS + (negBlocks > NEG_BLOCKS ? negBlocks : NEG_BLOCKS);
    k_loss<<<lossGrid, 256, 0, stream>>>(cla, reg, anchor, neg, dA, dF, dC,
                                         B, S, cnt, recs,
                                         pos_loss, neg_loss, neg_cnt);

    k_final<<<1, 1, 0, stream>>>(cnt, neg_cnt, pos_loss, neg_loss, B,
                                 (float*)d_out);
}

// Round 5
// 153.495 us; speedup vs baseline: 1.1050x; 1.0238x over previous
//
#include <hip/hip_runtime.h>
#include <math.h>

#define MAXL 256

// Workspace layout (first 64 bytes zeroed via hipMemsetAsync):
//   ws + 0  : int    pos_count (P)
//   ws + 4  : int    neg_count
//   ws + 8  : int    blocks_done
//   ws + 16 : double pos_loss
//   ws + 24 : double neg_loss
//   ws + 64 : PosRec records (compacted positive anchors)
struct __align__(16) PosRec {
    float t0, t1, t2, t3;
    int c2, h, w, pad;
};

// ---- Kernel 1: scan anchors, compute targets, compact positives ----
__global__ void __launch_bounds__(256)
k_scan(const float* __restrict__ anchor,
       const float* __restrict__ label,
       const int* __restrict__ dA,
       const int* __restrict__ dF,
       const int* __restrict__ dC,
       int N, int L, int maxRec,
       int* __restrict__ cnt,
       PosRec* __restrict__ recs)
{
    const int A = *dA;
    const int F = *dF;
    const float Cf = (float)(*dC);

    __shared__ float sh_cls[MAXL];
    __shared__ int   sh_occ[MAXL];
    const bool useLds = (L <= MAXL);
    if (useLds) {
        for (int j = threadIdx.x; j < L; j += blockDim.x)
            sh_cls[j] = label[(size_t)j * 5];
        __syncthreads();
        for (int j = threadIdx.x; j < L; j += blockDim.x) {
            float c = sh_cls[j];
            int o = 0;
            for (int k = 0; k < j; ++k) o += (sh_cls[k] == c) ? 1 : 0;
            sh_occ[j] = o;
        }
        __syncthreads();
    }

    const int tid = blockIdx.x * blockDim.x + threadIdx.x;
    const int nth = gridDim.x * blockDim.x;

    for (int n = tid; n < N; n += nth) {
        float albl = anchor[(size_t)n * 7 + 1];
        if (albl == -1.0f || albl == Cf) continue;

        float ax   = anchor[(size_t)n * 7 + 2];
        float ay   = anchor[(size_t)n * 7 + 3];
        float aw   = anchor[(size_t)n * 7 + 4];
        float ah   = anchor[(size_t)n * 7 + 5];
        float aocc = anchor[(size_t)n * 7 + 6];

        // first j with (class match && occurrence match); argmax(all-false)=0
        int gt = 0;
        for (int j = 0; j < L; ++j) {
            float cj; int oj;
            if (useLds) { cj = sh_cls[j]; oj = sh_occ[j]; }
            else {
                cj = label[(size_t)j * 5];
                oj = 0;
                for (int k = 0; k < j; ++k) oj += (label[(size_t)k * 5] == cj) ? 1 : 0;
            }
            if (cj == albl && (float)oj == aocc) { gt = j; break; }
        }
        const float* g = label + (size_t)gt * 5;

        PosRec r;
        r.t0 = (g[1] - ax) / aw;
        r.t1 = (g[2] - ay) / ah;
        r.t2 = logf(g[3] / aw);
        r.t3 = logf(g[4] / ah);
        int tmp = n / A;
        int ai  = n - tmp * A;
        r.h = tmp % F;
        r.w = tmp / F;
        r.c2 = ai * 2;
        r.pad = 0;

        int slot = atomicAdd(cnt, 1);
        if (slot < maxRec) recs[slot] = r;
    }
}

// ---- Kernel 2: fused pos + neg + finalize (last-block-done) ----
#define POS_BLOCKS 16
#define CMAX 8   // neg chunks (of 64 samples) buffered in registers per pass

__global__ void __launch_bounds__(256)
k_loss(const float* __restrict__ cla,
       const float* __restrict__ reg,
       const float* __restrict__ anchor,
       const int* __restrict__ neg,
       const int* __restrict__ dA,
       const int* __restrict__ dF,
       const int* __restrict__ dC,
       int B, int S, int maxRec,
       int* __restrict__ cnt,
       const PosRec* __restrict__ recs,
       double* __restrict__ pos_loss,
       double* __restrict__ neg_loss,
       int* __restrict__ neg_cnt,
       int* __restrict__ done,
       float* __restrict__ out)
{
    const int A = *dA;
    const int F = *dF;
    const size_t hw = (size_t)F * F;
    const int P = *cnt;
    const int lane = threadIdx.x & 63;

    if (blockIdx.x < POS_BLOCKS) {
        // -------- positive losses: P*B independent tasks --------
        const int tid = blockIdx.x * blockDim.x + threadIdx.x;
        const int nth = POS_BLOCKS * blockDim.x;
        int Pc = (P < maxRec) ? P : maxRec;
        const int T = Pc * B;

        double acc = 0.0;
        for (int task = tid; task < T; task += nth) {
            int p = task / B;
            int b = task - p * B;
            PosRec r = recs[p];
            int c4 = r.c2 * 2;

            size_t regBase = (((size_t)b * (4 * A) + c4) * F + r.h) * F + r.w;
            float d0 = reg[regBase]          - r.t0;
            float d1 = reg[regBase +     hw] - r.t1;
            float d2 = reg[regBase + 2 * hw] - r.t2;
            float d3 = reg[regBase + 3 * hw] - r.t3;

            float lr = 0.0f, ad;
            ad = fabsf(d0); lr += (ad < 1.0f) ? 0.5f * d0 * d0 : ad - 0.5f;
            ad = fabsf(d1); lr += (ad < 1.0f) ? 0.5f * d1 * d1 : ad - 0.5f;
            ad = fabsf(d2); lr += (ad < 1.0f) ? 0.5f * d2 * d2 : ad - 0.5f;
            ad = fabsf(d3); lr += (ad < 1.0f) ? 0.5f * d3 * d3 : ad - 0.5f;
            lr *= 0.25f;

            size_t claBase = (((size_t)b * (2 * A) + r.c2) * F + r.h) * F + r.w;
            float x0 = cla[claBase];
            float x1 = cla[claBase + hw];
            float m  = fmaxf(x0, x1);
            float lse = m + logf(expf(x0 - m) + expf(x1 - m));

            acc += (double)((lse - x1) + 4.0f * lr);
        }
        for (int off = 32; off > 0; off >>= 1) acc += __shfl_down(acc, off, 64);
        if (lane == 0 && acc != 0.0) atomicAdd(pos_loss, acc);
    } else {
        // -------- negatives: one wave per batch row, gathers parallelized --------
        const float Cf = (float)(*dC);
        int gwave = (blockIdx.x - POS_BLOCKS) * (blockDim.x >> 6) + (threadIdx.x >> 6);
        if (gwave < B) {
            int b = gwave;
            const int limit = 3 * P;
            const unsigned long long lanemask = (1ull << lane) - 1ull;

            int base = 0;
            float lsum = 0.0f;
            int lcnt = 0;

            for (int g0 = 0; g0 < S; g0 += 64 * CMAX) {
                int   idxr[CMAX];
                float lblr[CMAX];

                // round 1: coalesced index loads (all issued independently)
                #pragma unroll
                for (int c = 0; c < CMAX; ++c) {
                    int s = g0 + c * 64 + lane;
                    idxr[c] = (s < S) ? neg[(size_t)b * S + s] : 0;
                }
                // round 2: parallel label gathers
                #pragma unroll
                for (int c = 0; c < CMAX; ++c) {
                    int s = g0 + c * 64 + lane;
                    lblr[c] = (s < S) ? anchor[(size_t)idxr[c] * 7 + 1] : -2.0f;
                }
                // VALU cumsum chain + round 3: parallel cls gathers (predicated acc)
                #pragma unroll
                for (int c = 0; c < CMAX; ++c) {
                    int s = g0 + c * 64 + lane;
                    bool valid = (s < S);
                    bool isneg = valid && (lblr[c] == Cf);
                    unsigned long long mask = __ballot(isneg);
                    int pre = __popcll(mask & lanemask);
                    int cum = base + pre + (isneg ? 1 : 0);   // inclusive cumsum
                    bool inc = isneg && (cum <= limit);
                    base += __popcll(mask);

                    int idx = idxr[c];
                    int tmp = idx / A;
                    int ai  = idx - tmp * A;
                    int h   = tmp % F;
                    int w2  = tmp / F;
                    size_t claBase = (((size_t)b * (2 * A) + ai * 2) * F + h) * F + w2;
                    float x0 = valid ? cla[claBase]      : 0.0f;
                    float x1 = valid ? cla[claBase + hw] : 0.0f;
                    float m  = fmaxf(x0, x1);
                    float l  = m + logf(expf(x0 - m) + expf(x1 - m)) - x0;
                    lsum += inc ? l : 0.0f;
                    lcnt += inc ? 1 : 0;
                }
            }
            for (int off = 32; off > 0; off >>= 1) {
                lsum += __shfl_down(lsum, off, 64);
                lcnt += __shfl_down(lcnt, off, 64);
            }
            if (lane == 0 && lcnt != 0) {
                atomicAdd(neg_loss, (double)lsum);
                atomicAdd(neg_cnt, lcnt);
            }
        }
    }

    // -------- finalize: last block to finish writes the output --------
    __syncthreads();
    if (threadIdx.x == 0) {
        __threadfence();
        int t = atomicAdd(done, 1);
        if (t == (int)gridDim.x - 1) {
            __threadfence();
            double denom = (double)(B * P + *neg_cnt);
            out[0] = (float)((*pos_loss + *neg_loss) / denom);
        }
    }
}

extern "C" void kernel_launch(void* const* d_in, const int* in_sizes, int n_in,
                              void* d_out, int out_size, void* d_ws, size_t ws_size,
                              hipStream_t stream) {
    const float* cla    = (const float*)d_in[0];
    const float* reg    = (const float*)d_in[1];
    const float* label  = (const float*)d_in[2];
    const float* anchor = (const float*)d_in[3];
    const int*   neg    = (const int*)d_in[4];
    const int*   dA     = (const int*)d_in[5];
    const int*   dF     = (const int*)d_in[6];
    const int*   dC     = (const int*)d_in[7];

    int N = in_sizes[3] / 7;           // A*F*F
    int L = in_sizes[2] / 5;           // num labels
    int B = in_sizes[0] / (2 * N);     // batch
    int S = in_sizes[4] / B;           // neg samples per batch

    char* ws = (char*)d_ws;
    int*    cnt      = (int*)(ws + 0);
    int*    neg_cnt  = (int*)(ws + 4);
    int*    done     = (int*)(ws + 8);
    double* pos_loss = (double*)(ws + 16);
    double* neg_loss = (double*)(ws + 24);
    PosRec* recs     = (PosRec*)(ws + 64);
    int maxRec = (int)((ws_size - 64) / sizeof(PosRec));

    hipMemsetAsync(ws, 0, 64, stream);

    int scanGrid = 256;   // grid-stride over N
    k_scan<<<scanGrid, 256, 0, stream>>>(anchor, label, dA, dF, dC,
                                         N, L, maxRec, cnt, recs);

    int negBlocks = (B + 3) / 4;              // 4 waves per 256-thread block
    int lossGrid = POS_BLOCKS + negBlocks;
    k_loss<<<lossGrid, 256, 0, stream>>>(cla, reg, anchor, neg, dA, dF, dC,
                                         B, S, maxRec, cnt, recs,
                                         pos_loss, neg_loss, neg_cnt, done,
                                         (float*)d_out);
}